// Round 9
// baseline (1239.104 us; speedup 1.0000x reference)
//
#include <hip/hip_runtime.h>

// SNN fused forward: 3-layer LIF, T=100, B=32768, dims 128->256->256->8.
// R6: occupancy attack. Block = 16 rows, 1024 threads (16 waves), each wave
// owns 16 layer-1 cols => per-wave W1 hi/lo fp16 frags = 64 VGPRs (was 128).
// __launch_bounds__(1024,4) pins regs <=128 -> 4 waves/SIMD (2x TLP vs R3/R4,
// which were latency-bound at 2 waves/SIMD with ~30% stall).
// Spikes ballot-packed, double-buffered planes, 1 barrier/step (R3 scheme).
// Output layer folded into Z = sum_t c_t * s1_t (c_t via in-register
// recurrence, off the spike path); out = Z @ W2 via LDS atomics.

typedef _Float16 f16;
typedef _Float16 f16x8 __attribute__((ext_vector_type(8)));
typedef float    f32x4 __attribute__((ext_vector_type(4)));
typedef unsigned int u32;
typedef u32      u32x2 __attribute__((ext_vector_type(2)));
typedef unsigned long long u64;

#define SIM_T   100
#define MROWS   16
#define BLOCKSZ 1024
#define RECIP2048 4.8828125e-4f

#define MFMA16(a, b, c) __builtin_amdgcn_mfma_f32_16x16x32_f16((a), (b), (c), 0, 0, 0)

__global__ __launch_bounds__(BLOCKSZ, 4)
void snn_fused(const float* __restrict__ input,
               const float* __restrict__ W0,
               const float* __restrict__ W1,
               const float* __restrict__ W2,
               float* __restrict__ out)
{
    // Spike plane: addr(r,k) = ((k>>3)*16 + ((r + (k>>3)) & 15))*16 + (k&7)*2
    // (k>>3 = 16B chunk "slot", rows rotated per slot). A-frag ds_read_b128 is
    // 16 contiguous bytes; per-slot lane sets cover 256B => 2-way max (free).
    __shared__ __align__(16) char spk[2][8192];
    __shared__ float h2acc[MROWS * 8];

    const int tid  = threadIdx.x;
    const int wv   = tid >> 6;      // wave 0..15: owns layer-0/1 cols [16wv,16wv+16)
    const int ln   = tid & 63;
    const int mrow = ln & 15;       // MFMA A-row / B-col; spike-write row
    const int g    = ln >> 4;       // MFMA k-group 0..3
    const int row0 = blockIdx.x * MROWS;
    const int n0   = wv * 16;

    if (tid < MROWS * 8) h2acc[tid] = 0.0f;

    // ---- stage input tile into LDS (overlays spk[0]) ----
    float* instage = (float*)&spk[0][0];
    instage[tid]        = input[(size_t)row0 * 128 + tid];
    instage[tid + 1024] = input[(size_t)row0 * 128 + tid + 1024];
    __syncthreads();

    // ---- input A-fragments, exact fp16 hi/lo split ----
    f16x8 xh[4], xl[4];
    #pragma unroll
    for (int kc = 0; kc < 4; ++kc) {
        const float* p = instage + mrow * 128 + kc * 32 + g * 8;
        f16x8 vh, vl;
        #pragma unroll
        for (int e = 0; e < 8; ++e) {
            const float x = p[e];
            const f16 h = (f16)x;
            vh[e] = h;
            vl[e] = (f16)((x - (float)h) * 2048.0f);
        }
        xh[kc] = vh; xl[kc] = vl;
    }

    // ---- H0 = input @ W0 via MFMA: hi*hi + (hi*lo + lo*hi)/2048 ----
    f32x4 h0a = (f32x4){0, 0, 0, 0}, h0b = (f32x4){0, 0, 0, 0};
    {
        const int col = n0 + mrow;
        #pragma unroll
        for (int kc = 0; kc < 4; ++kc) {
            const int kb = kc * 32 + g * 8;
            f16x8 bh, bl;
            #pragma unroll
            for (int e = 0; e < 8; ++e) {
                const float w = W0[(kb + e) * 256 + col];
                const f16 h = (f16)w;
                bh[e] = h;
                bl[e] = (f16)((w - (float)h) * 2048.0f);
            }
            h0a = MFMA16(xh[kc], bh, h0a);
            h0b = MFMA16(xh[kc], bl, h0b);
            h0b = MFMA16(xl[kc], bh, h0b);
        }
    }

    // Layer-0 state in MFMA C-layout: elem q -> (row g*4+q, col n0+mrow)
    float H0c[4], syn0[4], mem0[4];
    #pragma unroll
    for (int q = 0; q < 4; ++q) {
        H0c[q]  = h0a[q] + RECIP2048 * h0b[q];
        syn0[q] = 0.0f;
        mem0[q] = 0.0f;
    }

    // ---- W1 -> VGPRs, exact fp16 hi/lo split (64 VGPRs/wave) ----
    f16x8 whi[8], wlo[8];
    {
        const int col = n0 + mrow;
        #pragma unroll
        for (int kc = 0; kc < 8; ++kc) {
            const int kb = kc * 32 + g * 8;
            f16x8 vh, vl;
            #pragma unroll
            for (int e = 0; e < 8; ++e) {
                const float w = W1[(kb + e) * 256 + col];
                const f16 h = (f16)w;
                vh[e] = h;
                vl[e] = (f16)((w - (float)h) * 2048.0f);
            }
            whi[kc] = vh; wlo[kc] = vl;
        }
    }

    // ---- precomputed LDS addresses ----
    // Spike write: lane (mrow,g) writes row mrow, cols n0+g*4..+3 => one b64.
    int wba;
    {
        const int slot = wv * 2 + (g >> 1);
        wba = (slot * 16 + ((mrow + slot) & 15)) * 16 + (g & 1) * 8;
    }
    const int shamt2 = (mrow >> 2) * 16 + g * 4;   // bit offset in ballot word
    // A-frag reads: slot = kc*4+g; ra[kc+4] = ra[kc] + 4096 (rot has period 4).
    int ra[4];
    #pragma unroll
    for (int kc = 0; kc < 4; ++kc) {
        const int slot = kc * 4 + g;
        ra[kc] = (slot * 16 + ((mrow + slot) & 15)) * 16;
    }

    float syn1[4], mem1[4], Zc[4];
    #pragma unroll
    for (int q = 0; q < 4; ++q) { syn1[q] = 0.0f; mem1[q] = 0.0f; Zc[q] = 0.0f; }

    // c_tau = 20*(0.9^n - 0.85^n), n = 99-t: forward recurrence (off spike path)
    float U = 20.0f * exp2f(-15.0483062f);   // 20 * 0.9^99
    float V = 20.0f * exp2f(-23.2120601f);   // 20 * 0.85^99

    __syncthreads();   // instage reads done; spk becomes spike planes

    int buf = 0;
    #pragma unroll 1
    for (int t = 0; t < SIM_T; ++t) {
        // ---- layer 0: ballot spikes from OLD mem0; state update (old syn0) ----
        u64 bal[4];
        #pragma unroll
        for (int q = 0; q < 4; ++q) {
            const float m = mem0[q], s = syn0[q];
            const bool fire = m > 1.0f;
            bal[q] = __ballot(fire);
            const float f = fire ? 1.0f : 0.0f;
            mem0[q] = fmaf(0.85f, m, s) - f;
            syn0[q] = fmaf(0.9f, s, H0c[q]);
        }
        // bal[q] bit (g'*16+m') = spike(row g'*4+q, col n0+m').
        // Lane (mrow,g) needs row mrow, cols n0+g*4..+3:
        //   word q = mrow&3, bits [(mrow>>2)*16 + g*4 .. +4)
        {
            const int rq = mrow & 3;
            const u64 b01 = (rq & 1) ? bal[1] : bal[0];
            const u64 b23 = (rq & 1) ? bal[3] : bal[2];
            const u64 bw  = (rq & 2) ? b23 : b01;
            const u32 bits = (u32)(bw >> shamt2) & 0xFu;
            u32x2 pk;
            pk.x = ((bits & 1u) ? 0x3C00u : 0u) | ((bits & 2u) ? 0x3C000000u : 0u);
            pk.y = ((bits & 4u) ? 0x3C00u : 0u) | ((bits & 8u) ? 0x3C000000u : 0u);
            *(u32x2*)(&spk[0][0] + buf + wba) = pk;
        }
        __syncthreads();   // plane ready (prev plane's reads fenced by prev barrier)

        // ---- layer 1: h1 = s0 @ (Whi + Wlo/2048), 16 MFMAs ----
        f32x4 ah = (f32x4){0, 0, 0, 0}, al = (f32x4){0, 0, 0, 0};
        const char* base = &spk[0][0] + buf;
        #pragma unroll
        for (int kc = 0; kc < 8; ++kc) {
            const f16x8 a = *(const f16x8*)(base + ra[kc & 3] + (kc >> 2) * 4096);
            ah = MFMA16(a, whi[kc], ah);
            al = MFMA16(a, wlo[kc], al);
        }

        const float ctau = U - V;
        U *= 1.1111112f;   // /0.9
        V *= 1.1764706f;   // /0.85

        // ---- layer-1 state + folded output accumulation ----
        #pragma unroll
        for (int q = 0; q < 4; ++q) {
            const float h1 = ah[q] + RECIP2048 * al[q];
            const float m = mem1[q], s = syn1[q];
            const bool fire = m > 1.0f;       // spike from OLD mem1
            const float f = fire ? 1.0f : 0.0f;
            Zc[q]   = fmaf(ctau, f, Zc[q]);
            mem1[q] = fmaf(0.85f, m, s) - f;
            syn1[q] = fmaf(0.9f, s, h1);
        }
        buf ^= 8192;
    }

    // ---- out = Z @ W2 via LDS atomic reduction (staggered to cut contention) ----
    {
        const float* w2 = W2 + (n0 + mrow) * 8;
        #pragma unroll
        for (int q = 0; q < 4; ++q) {
            const int r = g * 4 + q;
            const float z = Zc[q];
            #pragma unroll
            for (int oo = 0; oo < 8; ++oo) {
                const int o = (oo + mrow) & 7;
                atomicAdd(&h2acc[r * 8 + o], z * w2[o]);
            }
        }
    }
    __syncthreads();
    if (tid < MROWS * 8)
        out[(size_t)row0 * 8 + tid] = h2acc[tid];
}

extern "C" void kernel_launch(void* const* d_in, const int* in_sizes, int n_in,
                              void* d_out, int out_size, void* d_ws, size_t ws_size,
                              hipStream_t stream) {
    const float* input = (const float*)d_in[0];
    const float* W0    = (const float*)d_in[1];
    const float* W1    = (const float*)d_in[2];
    const float* W2    = (const float*)d_in[3];
    float* outp = (float*)d_out;
    const int B    = in_sizes[0] / 128;
    const int grid = B / MROWS;
    snn_fused<<<grid, BLOCKSZ, 0, stream>>>(input, W0, W1, W2, outp);
}